// Round 2
// baseline (910.507 us; speedup 1.0000x reference)
//
#include <hip/hip_runtime.h>
#include <hip/hip_bf16.h>

typedef __attribute__((ext_vector_type(8))) short bf16x8;
typedef __attribute__((ext_vector_type(4))) float f32x4;

#define BB 4
#define TT 16
#define T0 12
#define LL 64
#define CC 512
#define HH 8
#define HD 64
#define NQ (T0*LL)        // 768 queries per (b,h)
#define NCTX (TT*LL)      // 1024 cross keys
#define NKEY (NCTX+LL)    // 1088 total keys

__device__ __forceinline__ float bf2f(ushort u) {
  union { unsigned int i; float f; } x; x.i = ((unsigned int)u) << 16; return x.f;
}
__device__ __forceinline__ ushort f2bf(float f) {
  union { float f; unsigned int i; } x; x.f = f;
  unsigned int r = x.i + 0x7fffu + ((x.i >> 16) & 1u);  // round-to-nearest-even
  return (ushort)(r >> 16);
}
__device__ __forceinline__ bf16x8 load_frag_f32(const float* __restrict__ p) {
  f32x4 a = *(const f32x4*)p;
  f32x4 b = *(const f32x4*)(p + 4);
  bf16x8 r;
  r[0] = (short)f2bf(a[0]); r[1] = (short)f2bf(a[1]);
  r[2] = (short)f2bf(a[2]); r[3] = (short)f2bf(a[3]);
  r[4] = (short)f2bf(b[0]); r[5] = (short)f2bf(b[1]);
  r[6] = (short)f2bf(b[2]); r[7] = (short)f2bf(b[3]);
  return r;
}

// C[m,n] = sum_k A[m,k]*W[n,k] (+bias[n]).  A: f32 or bf16 (ABF), W: f32,
// C: bf16 or f32 (OBF). One wave = one 16x16 tile via mfma_f32_16x16x32_bf16.
// A-frag: lane holds A[m=mt*16+(lane&15)][k0+(lane>>4)*8+j]  (contiguous 8)
// D: row = mt*16+(lane>>4)*4+r, col = nt*16+(lane&15)   [m89 layout]
template<int ABF, int OBF>
__global__ __launch_bounds__(256) void gemm16(const void* __restrict__ Av,
                                              const float* __restrict__ W,
                                              const float* __restrict__ bias,
                                              void* __restrict__ Cv,
                                              int M, int N, int K) {
  int wave = (blockIdx.x << 2) + (threadIdx.x >> 6);
  int lane = threadIdx.x & 63;
  int ntiles = N >> 4;
  int mt = wave / ntiles;
  int nt = wave - mt * ntiles;
  if (mt * 16 >= M) return;
  int l15 = lane & 15;
  int ko  = (lane >> 4) << 3;
  f32x4 acc = {0.f, 0.f, 0.f, 0.f};
  if (ABF) {
    const ushort* Ap = (const ushort*)Av + (size_t)(mt * 16 + l15) * K + ko;
    const float*  Wp = W + (size_t)(nt * 16 + l15) * K + ko;
    for (int k = 0; k < K; k += 32) {
      bf16x8 a = *(const bf16x8*)(Ap + k);
      bf16x8 b = load_frag_f32(Wp + k);
      acc = __builtin_amdgcn_mfma_f32_16x16x32_bf16(a, b, acc, 0, 0, 0);
    }
  } else {
    const float* Ap = (const float*)Av + (size_t)(mt * 16 + l15) * K + ko;
    const float* Wp = W + (size_t)(nt * 16 + l15) * K + ko;
    for (int k = 0; k < K; k += 32) {
      bf16x8 a = load_frag_f32(Ap + k);
      bf16x8 b = load_frag_f32(Wp + k);
      acc = __builtin_amdgcn_mfma_f32_16x16x32_bf16(a, b, acc, 0, 0, 0);
    }
  }
  int row0 = mt * 16 + ((lane >> 4) << 2);
  int col  = nt * 16 + l15;
  float bv = bias ? bias[col] : 0.f;
  if (OBF) {
    ushort* C = (ushort*)Cv;
#pragma unroll
    for (int r = 0; r < 4; ++r) C[(size_t)(row0 + r) * N + col] = f2bf(acc[r] + bv);
  } else {
    float* C = (float*)Cv;
#pragma unroll
    for (int r = 0; r < 4; ++r) C[(size_t)(row0 + r) * N + col] = acc[r] + bv;
  }
}

// One wave per (b, h, query n). Scores for 1088 keys in LDS, wave-shuffle
// softmax, coalesced PV accumulation (thread = head-dim d). ws tensors bf16.
__global__ __launch_bounds__(64) void attn_kernel(const ushort* __restrict__ qkv,
                                                  const ushort* __restrict__ kctx,
                                                  const ushort* __restrict__ vctx,
                                                  const int* __restrict__ ctx_mask,
                                                  ushort* __restrict__ aout) {
  __shared__ float qs[HD];
  __shared__ float sc[NKEY];
  int idx = blockIdx.x;
  int n = idx % NQ;
  int h = (idx / NQ) % HH;
  int b = idx / (NQ * HH);
  int t0 = n >> 6;
  int tid = threadIdx.x;
  int qrow = b * NQ + n;

  qs[tid] = bf2f(qkv[(size_t)qrow * 1536 + h * HD + tid]);
  __syncthreads();

  // ---- scores: thread handles keys j = tid + 64*it ----
  for (int it = 0; it < 17; ++it) {
    int j = tid + (it << 6);
    const ushort* krow;
    bool valid;
    if (j < NCTX) {
      int t = j >> 6;
      valid = (ctx_mask[b * TT + t] != 0) && (t != t0 + 4);
      krow = kctx + (size_t)(b * NCTX + j) * CC + h * HD;
    } else {
      valid = true;
      krow = qkv + (size_t)(b * NQ + t0 * LL + (j - NCTX)) * 1536 + CC + h * HD;
    }
    float s;
    if (valid) {
      float acc = 0.f;
      const bf16x8* kv = (const bf16x8*)krow;
#pragma unroll
      for (int p = 0; p < 8; ++p) {
        bf16x8 kk = kv[p];
#pragma unroll
        for (int e = 0; e < 8; ++e)
          acc += qs[p * 8 + e] * bf2f((ushort)kk[e]);
      }
      s = acc * 0.125f;  // hd^-0.5
    } else {
      s = -1e30f;
    }
    sc[j] = s;
  }
  __syncthreads();

  // ---- softmax over 1088 keys ----
  float mx = -1e30f;
#pragma unroll
  for (int it = 0; it < 17; ++it) mx = fmaxf(mx, sc[tid + (it << 6)]);
#pragma unroll
  for (int off = 32; off > 0; off >>= 1) mx = fmaxf(mx, __shfl_xor(mx, off, 64));
  float sum = 0.f;
  for (int it = 0; it < 17; ++it) {
    int j = tid + (it << 6);
    float p = __expf(sc[j] - mx);
    sc[j] = p;
    sum += p;
  }
#pragma unroll
  for (int off = 32; off > 0; off >>= 1) sum += __shfl_xor(sum, off, 64);
  __syncthreads();
  float inv = 1.f / sum;

  // ---- PV: thread d = tid accumulates out[d] ----
  float o = 0.f;
  const ushort* vbase = vctx + (size_t)(b * NCTX) * CC + h * HD + tid;
#pragma unroll 4
  for (int j = 0; j < NCTX; ++j)
    o += sc[j] * bf2f(vbase[(size_t)j * CC]);
  const ushort* vsbase = qkv + (size_t)(b * NQ + t0 * LL) * 1536 + 1024 + h * HD + tid;
#pragma unroll 4
  for (int l = 0; l < LL; ++l)
    o += sc[NCTX + l] * bf2f(vsbase[(size_t)l * 1536]);

  aout[(size_t)qrow * CC + h * HD + tid] = f2bf(o * inv);
}

extern "C" void kernel_launch(void* const* d_in, const int* in_sizes, int n_in,
                              void* d_out, int out_size, void* d_ws, size_t ws_size,
                              hipStream_t stream) {
  const float* x        = (const float*)d_in[0];  // (4, 768, 512) f32
  const float* x_ctx    = (const float*)d_in[1];  // (4, 16, 64, 512) f32
  const float* dx_ctx   = (const float*)d_in[2];  // (4, 16, 64, 512) f32
  const int*   ctx_mask = (const int*)d_in[3];    // (4, 16) int
  const float* qkv_w    = (const float*)d_in[4];  // (1536, 512) f32
  const float* k_w      = (const float*)d_in[5];  // (512, 512) f32
  const float* v_w      = (const float*)d_in[6];  // (512, 512) f32
  const float* proj_w   = (const float*)d_in[7];  // (512, 512) f32
  const float* proj_b   = (const float*)d_in[8];  // (512,) f32
  float* out = (float*)d_out;                     // (4, 768, 512) f32

  char* ws = (char*)d_ws;
  ushort* qkv  = (ushort*)(ws);                 // [3072,1536] bf16 = 9.4 MB
  ushort* kctx = (ushort*)(ws + 9437184);       // [4096,512]  bf16 = 4.2 MB
  ushort* vctx = (ushort*)(ws + 13631488);      // [4096,512]  bf16 = 4.2 MB
  ushort* aout = (ushort*)(ws + 17825792);      // [3072,512]  bf16 = 3.1 MB

  // qkv = x @ qkv_w.T : M=3072,N=1536,K=512 -> (192*96)/4 = 4608 blocks
  gemm16<0,1><<<4608, 256, 0, stream>>>(x, qkv_w, nullptr, qkv, 3072, 1536, 512);
  // k_ctx = dx_ctx @ k_w.T : M=4096,N=512
  gemm16<0,1><<<2048, 256, 0, stream>>>(dx_ctx, k_w, nullptr, kctx, 4096, 512, 512);
  // v_ctx = x_ctx @ v_w.T
  gemm16<0,1><<<2048, 256, 0, stream>>>(x_ctx, v_w, nullptr, vctx, 4096, 512, 512);
  // attention: one wave per (b,h,query)
  attn_kernel<<<BB * HH * NQ, 64, 0, stream>>>(qkv, kctx, vctx, ctx_mask, aout);
  // out = aout @ proj_w.T + proj_b : M=3072,N=512
  gemm16<1,0><<<1536, 256, 0, stream>>>(aout, proj_w, proj_b, out, 3072, 512, 512);
}

// Round 3
// 253.353 us; speedup vs baseline: 3.5938x; 3.5938x over previous
//
#include <hip/hip_runtime.h>
#include <hip/hip_bf16.h>

typedef __attribute__((ext_vector_type(8))) short bf16x8;
typedef __attribute__((ext_vector_type(4))) float f32x4;

#define BB 4
#define TT 16
#define NT0 12
#define LL 64
#define CC 512
#define HH 8
#define HD 64
#define NQ (NT0*LL)       // 768 queries per batch
#define NCTX (TT*LL)      // 1024 cross keys per batch

__device__ __forceinline__ float bf2f(ushort u) {
  union { unsigned int i; float f; } x; x.i = ((unsigned int)u) << 16; return x.f;
}
__device__ __forceinline__ ushort f2bf(float f) {
  union { float f; unsigned int i; } x; x.f = f;
  unsigned int r = x.i + 0x7fffu + ((x.i >> 16) & 1u);  // RNE
  return (ushort)(r >> 16);
}
__device__ __forceinline__ bf16x8 load_frag_f32(const float* __restrict__ p) {
  f32x4 a = *(const f32x4*)p;
  f32x4 b = *(const f32x4*)(p + 4);
  bf16x8 r;
  r[0] = (short)f2bf(a[0]); r[1] = (short)f2bf(a[1]);
  r[2] = (short)f2bf(a[2]); r[3] = (short)f2bf(a[3]);
  r[4] = (short)f2bf(b[0]); r[5] = (short)f2bf(b[1]);
  r[6] = (short)f2bf(b[2]); r[7] = (short)f2bf(b[3]);
  return r;
}

// weights f32 -> bf16, concatenated dst [qkv_w|k_w|v_w|proj_w]
__global__ __launch_bounds__(256) void cvt_weights(const float* __restrict__ w0,
                                                   const float* __restrict__ w1,
                                                   const float* __restrict__ w2,
                                                   const float* __restrict__ w3,
                                                   ushort* __restrict__ dst) {
  int i = blockIdx.x * 256 + threadIdx.x;  // float4 index, total 393216
  const float* src; int off;
  if (i < 196608)      { src = w0; off = 0; }
  else if (i < 262144) { src = w1; off = 196608; }
  else if (i < 327680) { src = w2; off = 262144; }
  else                 { src = w3; off = 327680; }
  f32x4 v = *(const f32x4*)(src + (size_t)(i - off) * 4);
  ushort4 o = { f2bf(v[0]), f2bf(v[1]), f2bf(v[2]), f2bf(v[3]) };
  *(ushort4*)(dst + (size_t)i * 4) = o;
}

// C[m,n] = sum_k A[m,k]*W[n,k]. A: f32 (ABF=0) or bf16 (ABF=1); W bf16 [N][K].
// Wave computes 16m x 64n (4 subtiles, A-frag reused 4x).
// MODE 0: C bf16 normal. MODE 1: CT bf16 transposed only (CT[col*TM+row]).
// MODE 2: qkv: col<1024 normal C; col>=1024 -> CT[(col-1024)*TM+row] (self-V^T).
// MODE 3: Cf f32 normal + bias.
template<int ABF, int MODE>
__global__ __launch_bounds__(256) void gemm_bf(const void* __restrict__ Av,
                                               const ushort* __restrict__ W,
                                               const float* __restrict__ bias,
                                               ushort* __restrict__ C,
                                               ushort* __restrict__ CT,
                                               float* __restrict__ Cf,
                                               int M, int N, int K, int TM) {
  int wave = (blockIdx.x << 2) + (threadIdx.x >> 6);
  int lane = threadIdx.x & 63;
  int l15 = lane & 15, kg = lane >> 4;
  int nt64 = N >> 6;
  int mt = wave / nt64;
  int nt = wave - mt * nt64;
  if (mt * 16 >= M) return;

  const ushort* Wp = W + (size_t)(nt * 64 + l15) * K + kg * 8;
  f32x4 acc[4] = {{0,0,0,0},{0,0,0,0},{0,0,0,0},{0,0,0,0}};

  if (ABF) {
    const ushort* Ap = (const ushort*)Av + (size_t)(mt * 16 + l15) * K + kg * 8;
    for (int k = 0; k < K; k += 32) {
      bf16x8 a = *(const bf16x8*)(Ap + k);
#pragma unroll
      for (int s = 0; s < 4; ++s) {
        bf16x8 w = *(const bf16x8*)(Wp + (size_t)s * 16 * K + k);
        acc[s] = __builtin_amdgcn_mfma_f32_16x16x32_bf16(a, w, acc[s], 0, 0, 0);
      }
    }
  } else {
    const float* Ap = (const float*)Av + (size_t)(mt * 16 + l15) * K + kg * 8;
    for (int k = 0; k < K; k += 32) {
      bf16x8 a = load_frag_f32(Ap + k);
#pragma unroll
      for (int s = 0; s < 4; ++s) {
        bf16x8 w = *(const bf16x8*)(Wp + (size_t)s * 16 * K + k);
        acc[s] = __builtin_amdgcn_mfma_f32_16x16x32_bf16(a, w, acc[s], 0, 0, 0);
      }
    }
  }

  int row0 = mt * 16 + (kg << 2);
#pragma unroll
  for (int s = 0; s < 4; ++s) {
    int col = nt * 64 + s * 16 + l15;
    if (MODE == 0) {
#pragma unroll
      for (int r = 0; r < 4; ++r) C[(size_t)(row0 + r) * N + col] = f2bf(acc[s][r]);
    } else if (MODE == 1) {
      ushort4 o = { f2bf(acc[s][0]), f2bf(acc[s][1]), f2bf(acc[s][2]), f2bf(acc[s][3]) };
      *(ushort4*)(CT + (size_t)col * TM + row0) = o;
    } else if (MODE == 2) {
      if (nt * 64 + s * 16 >= 1024) {
        ushort4 o = { f2bf(acc[s][0]), f2bf(acc[s][1]), f2bf(acc[s][2]), f2bf(acc[s][3]) };
        *(ushort4*)(CT + (size_t)(col - 1024) * TM + row0) = o;
      } else {
#pragma unroll
        for (int r = 0; r < 4; ++r) C[(size_t)(row0 + r) * N + col] = f2bf(acc[s][r]);
      }
    } else {
      float bv = bias[col];
#pragma unroll
      for (int r = 0; r < 4; ++r) Cf[(size_t)(row0 + r) * N + col] = acc[s][r] + bv;
    }
  }
}

// Flash attention, S^T orientation. Block = (b, h, frame t0); 4 waves x 16 q.
// Online softmax state per lane (col q = lane&15). Skips fully-masked frames.
__global__ __launch_bounds__(256) void flash_attn(const ushort* __restrict__ qkv,
                                                  const ushort* __restrict__ kctx,
                                                  const ushort* __restrict__ vctxT,
                                                  const ushort* __restrict__ vselfT,
                                                  const int* __restrict__ ctx_mask,
                                                  ushort* __restrict__ aout) {
  __shared__ ushort Pt[4][16 * 72];  // per-wave P^T strip: [q 16][key 64] stride 72
  int blk = blockIdx.x;              // b*96 + h*12 + t0
  int t0 = blk % NT0;
  int h  = (blk / NT0) % HH;
  int b  = blk / (NT0 * HH);
  int tid = threadIdx.x, wv = tid >> 6, lane = tid & 63;
  int l15 = lane & 15, kg = lane >> 4;

  // Q B-frags (n-side rows = q = l15), d split in two halves
  int qrow = b * NQ + t0 * LL + wv * 16 + l15;
  const ushort* qp = qkv + (size_t)qrow * 1536 + h * HD + kg * 8;
  bf16x8 q0 = *(const bf16x8*)qp;
  bf16x8 q1 = *(const bf16x8*)(qp + 32);

  f32x4 acc[4] = {{0,0,0,0},{0,0,0,0},{0,0,0,0},{0,0,0,0}};
  float Mr = -INFINITY, Lr = 0.f;
  ushort* myPt = &Pt[wv][0];

  for (int kt = 0; kt <= TT; ++kt) {
    const ushort* kbase; int kstr;
    if (kt < TT) {
      if (!(ctx_mask[b * TT + kt] != 0 && kt != t0 + 4)) continue;
      kbase = kctx + (size_t)(b * NCTX + kt * LL) * CC + h * HD;
      kstr = CC;
    } else {
      kbase = qkv + (size_t)(b * NQ + t0 * LL) * 1536 + CC + h * HD;
      kstr = 1536;
    }

    // S^T tile: 64 keys x 16 q, rows=key (A=K), cols=q (B=Q)
    f32x4 s[4];
#pragma unroll
    for (int st = 0; st < 4; ++st) {
      const ushort* kp = kbase + (size_t)(st * 16 + l15) * kstr + kg * 8;
      bf16x8 k0 = *(const bf16x8*)kp;
      bf16x8 k1 = *(const bf16x8*)(kp + 32);
      f32x4 z = {0, 0, 0, 0};
      z = __builtin_amdgcn_mfma_f32_16x16x32_bf16(k0, q0, z, 0, 0, 0);
      z = __builtin_amdgcn_mfma_f32_16x16x32_bf16(k1, q1, z, 0, 0, 0);
      s[st] = z * 0.125f;  // hd^-0.5
    }

    // per-q (= l15) online softmax; lanes sharing l15 differ in bits 4..5
    float tmax = -INFINITY;
#pragma unroll
    for (int st = 0; st < 4; ++st)
#pragma unroll
      for (int r = 0; r < 4; ++r) tmax = fmaxf(tmax, s[st][r]);
    tmax = fmaxf(tmax, __shfl_xor(tmax, 16, 64));
    tmax = fmaxf(tmax, __shfl_xor(tmax, 32, 64));
    float Mn = fmaxf(Mr, tmax);
    float alpha = __expf(Mr - Mn);
    Mr = Mn;
    float tsum = 0.f;
#pragma unroll
    for (int st = 0; st < 4; ++st)
#pragma unroll
      for (int r = 0; r < 4; ++r) {
        float p = __expf(s[st][r] - Mr);
        s[st][r] = p;
        tsum += p;
      }
    tsum += __shfl_xor(tsum, 16, 64);
    tsum += __shfl_xor(tsum, 32, 64);
    Lr = Lr * alpha + tsum;
#pragma unroll
    for (int d = 0; d < 4; ++d) acc[d] *= alpha;

    // write P^T (C-layout rows = 4 contiguous keys) to wave-private LDS strip
#pragma unroll
    for (int st = 0; st < 4; ++st) {
      ushort4 pk = { f2bf(s[st][0]), f2bf(s[st][1]), f2bf(s[st][2]), f2bf(s[st][3]) };
      *(ushort4*)(myPt + l15 * 72 + st * 16 + kg * 4) = pk;
    }

    // PV: D[d][q] += V^T[d][key] . P^T-as-B[q][key]
    const ushort* vtb; int vtN;
    if (kt < TT) { vtb = vctxT + (size_t)h * HD * (BB * NCTX) + b * NCTX + kt * LL; vtN = BB * NCTX; }
    else         { vtb = vselfT + (size_t)h * HD * (BB * NQ) + b * NQ + t0 * LL;   vtN = BB * NQ; }
#pragma unroll
    for (int kc = 0; kc < 2; ++kc) {
      bf16x8 pb = *(const bf16x8*)(myPt + l15 * 72 + kc * 32 + kg * 8);
#pragma unroll
      for (int d = 0; d < 4; ++d) {
        const ushort* vp = vtb + (size_t)(d * 16 + l15) * vtN + kc * 32 + kg * 8;
        bf16x8 vf = *(const bf16x8*)vp;
        acc[d] = __builtin_amdgcn_mfma_f32_16x16x32_bf16(vf, pb, acc[d], 0, 0, 0);
      }
    }
  }

  float inv = 1.f / Lr;
  int orow = b * NQ + t0 * LL + wv * 16 + l15;  // col q = l15
#pragma unroll
  for (int d = 0; d < 4; ++d) {
    ushort4 o = { f2bf(acc[d][0] * inv), f2bf(acc[d][1] * inv),
                  f2bf(acc[d][2] * inv), f2bf(acc[d][3] * inv) };
    *(ushort4*)(aout + (size_t)orow * CC + h * HD + d * 16 + kg * 4) = o;
  }
}

extern "C" void kernel_launch(void* const* d_in, const int* in_sizes, int n_in,
                              void* d_out, int out_size, void* d_ws, size_t ws_size,
                              hipStream_t stream) {
  const float* x        = (const float*)d_in[0];
  const float* x_ctx    = (const float*)d_in[1];
  const float* dx_ctx   = (const float*)d_in[2];
  const int*   ctx_mask = (const int*)d_in[3];
  const float* qkv_w    = (const float*)d_in[4];
  const float* k_w      = (const float*)d_in[5];
  const float* v_w      = (const float*)d_in[6];
  const float* proj_w   = (const float*)d_in[7];
  const float* proj_b   = (const float*)d_in[8];
  float* out = (float*)d_out;

  ushort* ws = (ushort*)d_ws;   // element offsets (bf16)
  ushort* qkvwb  = ws;                    // 786432
  ushort* kwb    = ws + 786432;           // 262144
  ushort* vwb    = ws + 1048576;          // 262144
  ushort* pwb    = ws + 1310720;          // 262144
  ushort* qkv    = ws + 1572864;          // 3072x1536
  ushort* kctx   = ws + 6291456;          // 4096x512
  ushort* vctxT  = ws + 8388608;          // 512x4096
  ushort* vselfT = ws + 10485760;         // 512x3072
  ushort* aout   = ws + 12058624;         // 3072x512   (end 13631488 el = 27.3MB)

  cvt_weights<<<1536, 256, 0, stream>>>(qkv_w, k_w, v_w, proj_w, qkvwb);

  // qkv = x @ qkv_w.T (M=3072,N=1536): normal for Q/K cols, self-V^T for V cols
  gemm_bf<0,2><<<1152, 256, 0, stream>>>(x, qkvwb, nullptr, qkv, vselfT, nullptr,
                                         3072, 1536, 512, 3072);
  // k_ctx = dx_ctx @ k_w.T (M=4096,N=512), normal layout
  gemm_bf<0,0><<<512, 256, 0, stream>>>(dx_ctx, kwb, nullptr, kctx, nullptr, nullptr,
                                        4096, 512, 512, 0);
  // v_ctx^T = (x_ctx @ v_w.T)^T (CT[col*4096+row])
  gemm_bf<0,1><<<512, 256, 0, stream>>>(x_ctx, vwb, nullptr, nullptr, vctxT, nullptr,
                                        4096, 512, 512, 4096);
  // fused flash attention: block per (b,h,frame)
  flash_attn<<<BB * HH * NT0, 256, 0, stream>>>(qkv, kctx, vctxT, vselfT, ctx_mask, aout);
  // out = aout @ proj_w.T + proj_b (f32 out)
  gemm_bf<1,3><<<384, 256, 0, stream>>>(aout, pwb, proj_b, nullptr, nullptr, out,
                                        3072, 512, 512, 0);
}

// Round 4
// 197.515 us; speedup vs baseline: 4.6098x; 1.2827x over previous
//
#include <hip/hip_runtime.h>
#include <hip/hip_bf16.h>

typedef __attribute__((ext_vector_type(8))) short bf16x8;
typedef __attribute__((ext_vector_type(4))) float f32x4;

#define BB 4
#define TT 16
#define NT0 12
#define LL 64
#define CC 512
#define HH 8
#define HD 64
#define NQ (NT0*LL)       // 768 queries per batch
#define NCTX (TT*LL)      // 1024 cross keys per batch

__device__ __forceinline__ float bf2f(ushort u) {
  union { unsigned int i; float f; } x; x.i = ((unsigned int)u) << 16; return x.f;
}
__device__ __forceinline__ ushort f2bf(float f) {
  union { float f; unsigned int i; } x; x.f = f;
  unsigned int r = x.i + 0x7fffu + ((x.i >> 16) & 1u);  // RNE
  return (ushort)(r >> 16);
}

// Convert f32 inputs -> bf16 workspace, layout [qkv_w|k_w|v_w|proj_w|x|x_ctx|dx_ctx]
__global__ __launch_bounds__(256) void cvt_all(const float* __restrict__ w0,
                                               const float* __restrict__ w1,
                                               const float* __restrict__ w2,
                                               const float* __restrict__ w3,
                                               const float* __restrict__ x,
                                               const float* __restrict__ xc,
                                               const float* __restrict__ dxc,
                                               ushort* __restrict__ dst) {
  long i = (long)blockIdx.x * 256 + threadIdx.x;  // float4 index, total 1835008
  const float* src; long off;
  if (i < 196608)       { src = w0;  off = 0; }
  else if (i < 262144)  { src = w1;  off = 196608; }
  else if (i < 327680)  { src = w2;  off = 262144; }
  else if (i < 393216)  { src = w3;  off = 327680; }
  else if (i < 786432)  { src = x;   off = 393216; }
  else if (i < 1310720) { src = xc;  off = 786432; }
  else                  { src = dxc; off = 1310720; }
  f32x4 v = *(const f32x4*)(src + (i - off) * 4);
  ushort4 o = { f2bf(v[0]), f2bf(v[1]), f2bf(v[2]), f2bf(v[3]) };
  *(ushort4*)(dst + i * 4) = o;
}

// One wave: 32m x 64n tile, K=512 fixed, all-bf16, depth-1 register prefetch.
// OUTMODE 0: C bf16 row-major [*,N].  1: CT bf16 transposed CT[col*TM+row]
// (CT may be pre-offset for a column base).  2: Cf f32 row-major + bias.
template<int OUTMODE>
__device__ __forceinline__ void gemm_tile(const ushort* __restrict__ A,
                                          const ushort* __restrict__ W,
                                          ushort* __restrict__ C,
                                          ushort* __restrict__ CT,
                                          float* __restrict__ Cf,
                                          const float* __restrict__ bias,
                                          int mt, int nt, int N, int TM) {
  int lane = threadIdx.x & 63;
  int l15 = lane & 15, kg = lane >> 4;
  const ushort* Ap = A + (size_t)(mt * 32 + l15) * 512 + kg * 8;
  const ushort* Wp = W + (size_t)(nt * 64 + l15) * 512 + kg * 8;
  f32x4 acc[8] = {{0,0,0,0},{0,0,0,0},{0,0,0,0},{0,0,0,0},
                  {0,0,0,0},{0,0,0,0},{0,0,0,0},{0,0,0,0}};
  bf16x8 a0 = *(const bf16x8*)(Ap);
  bf16x8 a1 = *(const bf16x8*)(Ap + 8192);
  bf16x8 w0 = *(const bf16x8*)(Wp);
  bf16x8 w1 = *(const bf16x8*)(Wp + 8192);
  bf16x8 w2 = *(const bf16x8*)(Wp + 16384);
  bf16x8 w3 = *(const bf16x8*)(Wp + 24576);
#pragma unroll
  for (int k = 32; k <= 512; k += 32) {
    bf16x8 na0, na1, nw0, nw1, nw2, nw3;
    if (k < 512) {
      na0 = *(const bf16x8*)(Ap + k);
      na1 = *(const bf16x8*)(Ap + 8192 + k);
      nw0 = *(const bf16x8*)(Wp + k);
      nw1 = *(const bf16x8*)(Wp + 8192 + k);
      nw2 = *(const bf16x8*)(Wp + 16384 + k);
      nw3 = *(const bf16x8*)(Wp + 24576 + k);
    }
    acc[0] = __builtin_amdgcn_mfma_f32_16x16x32_bf16(a0, w0, acc[0], 0, 0, 0);
    acc[1] = __builtin_amdgcn_mfma_f32_16x16x32_bf16(a0, w1, acc[1], 0, 0, 0);
    acc[2] = __builtin_amdgcn_mfma_f32_16x16x32_bf16(a0, w2, acc[2], 0, 0, 0);
    acc[3] = __builtin_amdgcn_mfma_f32_16x16x32_bf16(a0, w3, acc[3], 0, 0, 0);
    acc[4] = __builtin_amdgcn_mfma_f32_16x16x32_bf16(a1, w0, acc[4], 0, 0, 0);
    acc[5] = __builtin_amdgcn_mfma_f32_16x16x32_bf16(a1, w1, acc[5], 0, 0, 0);
    acc[6] = __builtin_amdgcn_mfma_f32_16x16x32_bf16(a1, w2, acc[6], 0, 0, 0);
    acc[7] = __builtin_amdgcn_mfma_f32_16x16x32_bf16(a1, w3, acc[7], 0, 0, 0);
    a0 = na0; a1 = na1; w0 = nw0; w1 = nw1; w2 = nw2; w3 = nw3;
  }
#pragma unroll
  for (int hh = 0; hh < 2; ++hh) {
    int row = mt * 32 + hh * 16 + kg * 4;
#pragma unroll
    for (int s = 0; s < 4; ++s) {
      f32x4 v = acc[hh * 4 + s];
      int col = nt * 64 + s * 16 + l15;
      if (OUTMODE == 0) {
#pragma unroll
        for (int r = 0; r < 4; ++r) C[(size_t)(row + r) * N + col] = f2bf(v[r]);
      } else if (OUTMODE == 1) {
        ushort4 o = { f2bf(v[0]), f2bf(v[1]), f2bf(v[2]), f2bf(v[3]) };
        *(ushort4*)(CT + (size_t)col * TM + row) = o;
      } else {
        float bv = bias[col];
#pragma unroll
        for (int r = 0; r < 4; ++r) Cf[(size_t)(row + r) * N + col] = v[r] + bv;
      }
    }
  }
}

// Fused input GEMMs: blocks [0,576): qkv (x@qkv_w.T, self-V cols transposed);
// [576,832): kctx = dx_ctx@k_w.T; [832,1088): vctx^T = (x_ctx@v_w.T)^T.
__global__ __launch_bounds__(256) void gemm3(const ushort* __restrict__ xb,
                                             const ushort* __restrict__ dxb,
                                             const ushort* __restrict__ xcb,
                                             const ushort* __restrict__ qkvwb,
                                             const ushort* __restrict__ kwb,
                                             const ushort* __restrict__ vwb,
                                             ushort* __restrict__ qkv,
                                             ushort* __restrict__ vselfT,
                                             ushort* __restrict__ kctx,
                                             ushort* __restrict__ vctxT) {
  int blk = blockIdx.x;
  int wv = threadIdx.x >> 6;
  if (blk < 576) {
    int nt = blk / 24, mtb = blk % 24;
    int mt = mtb * 4 + wv;
    if (nt < 16)
      gemm_tile<0>(xb, qkvwb, qkv, nullptr, nullptr, nullptr, mt, nt, 1536, 0);
    else  // cols >= 1024 -> vselfT[col-1024][row]; pre-offset CT by -1024*TM
      gemm_tile<1>(xb, qkvwb, nullptr, vselfT - (size_t)1024 * 3072, nullptr, nullptr,
                   mt, nt, 1536, 3072);
  } else if (blk < 832) {
    int r = blk - 576;
    int nt = r & 7, mtb = r >> 3;
    gemm_tile<0>(dxb, kwb, kctx, nullptr, nullptr, nullptr, mtb * 4 + wv, nt, 512, 0);
  } else {
    int r = blk - 832;
    int nt = r & 7, mtb = r >> 3;
    gemm_tile<1>(xcb, vwb, nullptr, vctxT, nullptr, nullptr, mtb * 4 + wv, nt, 512, 4096);
  }
}

__global__ __launch_bounds__(256) void gemm_proj(const ushort* __restrict__ aout,
                                                 const ushort* __restrict__ pwb,
                                                 const float* __restrict__ bias,
                                                 float* __restrict__ out) {
  int blk = blockIdx.x;           // 192 blocks: 24 mtb x 8 nt
  int wv = threadIdx.x >> 6;
  int nt = blk & 7, mtb = blk >> 3;
  gemm_tile<2>(aout, pwb, nullptr, nullptr, out, bias, mtb * 4 + wv, nt, 512, 0);
}

// Flash attention, S^T orientation. Block = (b, h, frame t0); 4 waves x 16 q.
__global__ __launch_bounds__(256) void flash_attn(const ushort* __restrict__ qkv,
                                                  const ushort* __restrict__ kctx,
                                                  const ushort* __restrict__ vctxT,
                                                  const ushort* __restrict__ vselfT,
                                                  const int* __restrict__ ctx_mask,
                                                  ushort* __restrict__ aout) {
  __shared__ ushort Pt[4][16 * 72];  // per-wave P^T strip
  int blk = blockIdx.x;              // b*96 + h*12 + t0
  int t0 = blk % NT0;
  int h  = (blk / NT0) % HH;
  int b  = blk / (NT0 * HH);
  int tid = threadIdx.x, wv = tid >> 6, lane = tid & 63;
  int l15 = lane & 15, kg = lane >> 4;

  int qrow = b * NQ + t0 * LL + wv * 16 + l15;
  const ushort* qp = qkv + (size_t)qrow * 1536 + h * HD + kg * 8;
  bf16x8 q0 = *(const bf16x8*)qp;
  bf16x8 q1 = *(const bf16x8*)(qp + 32);

  f32x4 acc[4] = {{0,0,0,0},{0,0,0,0},{0,0,0,0},{0,0,0,0}};
  float Mr = -INFINITY, Lr = 0.f;
  ushort* myPt = &Pt[wv][0];

  for (int kt = 0; kt <= TT; ++kt) {
    const ushort* kbase; int kstr;
    if (kt < TT) {
      if (!(ctx_mask[b * TT + kt] != 0 && kt != t0 + 4)) continue;
      kbase = kctx + (size_t)(b * NCTX + kt * LL) * CC + h * HD;
      kstr = CC;
    } else {
      kbase = qkv + (size_t)(b * NQ + t0 * LL) * 1536 + CC + h * HD;
      kstr = 1536;
    }

    f32x4 s[4];
#pragma unroll
    for (int st = 0; st < 4; ++st) {
      const ushort* kp = kbase + (size_t)(st * 16 + l15) * kstr + kg * 8;
      bf16x8 k0 = *(const bf16x8*)kp;
      bf16x8 k1 = *(const bf16x8*)(kp + 32);
      f32x4 z = {0, 0, 0, 0};
      z = __builtin_amdgcn_mfma_f32_16x16x32_bf16(k0, q0, z, 0, 0, 0);
      z = __builtin_amdgcn_mfma_f32_16x16x32_bf16(k1, q1, z, 0, 0, 0);
      s[st] = z * 0.125f;
    }

    float tmax = -INFINITY;
#pragma unroll
    for (int st = 0; st < 4; ++st)
#pragma unroll
      for (int r = 0; r < 4; ++r) tmax = fmaxf(tmax, s[st][r]);
    tmax = fmaxf(tmax, __shfl_xor(tmax, 16, 64));
    tmax = fmaxf(tmax, __shfl_xor(tmax, 32, 64));
    float Mn = fmaxf(Mr, tmax);
    float alpha = __expf(Mr - Mn);
    Mr = Mn;
    float tsum = 0.f;
#pragma unroll
    for (int st = 0; st < 4; ++st)
#pragma unroll
      for (int r = 0; r < 4; ++r) {
        float p = __expf(s[st][r] - Mr);
        s[st][r] = p;
        tsum += p;
      }
    tsum += __shfl_xor(tsum, 16, 64);
    tsum += __shfl_xor(tsum, 32, 64);
    Lr = Lr * alpha + tsum;
#pragma unroll
    for (int d = 0; d < 4; ++d) acc[d] *= alpha;

#pragma unroll
    for (int st = 0; st < 4; ++st) {
      ushort4 pk = { f2bf(s[st][0]), f2bf(s[st][1]), f2bf(s[st][2]), f2bf(s[st][3]) };
      *(ushort4*)(myPt + l15 * 72 + st * 16 + kg * 4) = pk;
    }

    const ushort* vtb; int vtN;
    if (kt < TT) { vtb = vctxT + (size_t)h * HD * (BB * NCTX) + b * NCTX + kt * LL; vtN = BB * NCTX; }
    else         { vtb = vselfT + (size_t)h * HD * (BB * NQ) + b * NQ + t0 * LL;   vtN = BB * NQ; }
#pragma unroll
    for (int kc = 0; kc < 2; ++kc) {
      bf16x8 pb = *(const bf16x8*)(myPt + l15 * 72 + kc * 32 + kg * 8);
#pragma unroll
      for (int d = 0; d < 4; ++d) {
        const ushort* vp = vtb + (size_t)(d * 16 + l15) * vtN + kc * 32 + kg * 8;
        bf16x8 vf = *(const bf16x8*)vp;
        acc[d] = __builtin_amdgcn_mfma_f32_16x16x32_bf16(vf, pb, acc[d], 0, 0, 0);
      }
    }
  }

  float inv = 1.f / Lr;
  int orow = b * NQ + t0 * LL + wv * 16 + l15;
#pragma unroll
  for (int d = 0; d < 4; ++d) {
    ushort4 o = { f2bf(acc[d][0] * inv), f2bf(acc[d][1] * inv),
                  f2bf(acc[d][2] * inv), f2bf(acc[d][3] * inv) };
    *(ushort4*)(aout + (size_t)orow * CC + h * HD + d * 16 + kg * 4) = o;
  }
}

extern "C" void kernel_launch(void* const* d_in, const int* in_sizes, int n_in,
                              void* d_out, int out_size, void* d_ws, size_t ws_size,
                              hipStream_t stream) {
  const float* x        = (const float*)d_in[0];
  const float* x_ctx    = (const float*)d_in[1];
  const float* dx_ctx   = (const float*)d_in[2];
  const int*   ctx_mask = (const int*)d_in[3];
  const float* qkv_w    = (const float*)d_in[4];
  const float* k_w      = (const float*)d_in[5];
  const float* v_w      = (const float*)d_in[6];
  const float* proj_w   = (const float*)d_in[7];
  const float* proj_b   = (const float*)d_in[8];
  float* out = (float*)d_out;

  ushort* ws = (ushort*)d_ws;   // element offsets (bf16)
  ushort* qkvwb  = ws;                    //  786432
  ushort* kwb    = ws + 786432;           //  262144
  ushort* vwb    = ws + 1048576;          //  262144
  ushort* pwb    = ws + 1310720;          //  262144
  ushort* xb     = ws + 1572864;          // 1572864  (3072x512)
  ushort* xcb    = ws + 3145728;          // 2097152  (4096x512)
  ushort* dxb    = ws + 5242880;          // 2097152  (4096x512)
  ushort* qkv    = ws + 7340032;          // 3072x1536
  ushort* kctx   = ws + 12058624;         // 4096x512
  ushort* vctxT  = ws + 14155776;         // 512x4096
  ushort* vselfT = ws + 16252928;         // 512x3072
  ushort* aout   = ws + 17825792;         // 3072x512  (end 19398656 el = 38.8MB)

  cvt_all<<<7168, 256, 0, stream>>>(qkv_w, k_w, v_w, proj_w, x, x_ctx, dx_ctx, ws);
  gemm3<<<1088, 256, 0, stream>>>(xb, dxb, xcb, qkvwb, kwb, vwb,
                                  qkv, vselfT, kctx, vctxT);
  flash_attn<<<BB * HH * NT0, 256, 0, stream>>>(qkv, kctx, vctxT, vselfT, ctx_mask, aout);
  gemm_proj<<<192, 256, 0, stream>>>(aout, pwb, proj_b, out);
}

// Round 5
// 157.807 us; speedup vs baseline: 5.7698x; 1.2516x over previous
//
#include <hip/hip_runtime.h>
#include <hip/hip_bf16.h>

typedef __attribute__((ext_vector_type(8))) short bf16x8;
typedef __attribute__((ext_vector_type(4))) float f32x4;

#define BB 4
#define TT 16
#define NT0 12
#define LL 64
#define CC 512
#define HH 8
#define HD 64
#define NQ (NT0*LL)       // 768 queries per batch
#define NCTX (TT*LL)      // 1024 cross keys per batch

#define GPTR(x) ((__attribute__((address_space(1))) void*)(x))
#define SPTR(x) ((__attribute__((address_space(3))) void*)(x))

__device__ __forceinline__ float bf2f(ushort u) {
  union { unsigned int i; float f; } x; x.i = ((unsigned int)u) << 16; return x.f;
}
__device__ __forceinline__ ushort f2bf(float f) {
  union { float f; unsigned int i; } x; x.f = f;
  unsigned int r = x.i + 0x7fffu + ((x.i >> 16) & 1u);  // RNE
  return (ushort)(r >> 16);
}

// Convert f32 inputs -> bf16 workspace, layout [qkv_w|k_w|v_w|proj_w|x|x_ctx|dx_ctx]
__global__ __launch_bounds__(256) void cvt_all(const float* __restrict__ w0,
                                               const float* __restrict__ w1,
                                               const float* __restrict__ w2,
                                               const float* __restrict__ w3,
                                               const float* __restrict__ x,
                                               const float* __restrict__ xc,
                                               const float* __restrict__ dxc,
                                               ushort* __restrict__ dst) {
  long i = (long)blockIdx.x * 256 + threadIdx.x;  // float4 index, total 1835008
  const float* src; long off;
  if (i < 196608)       { src = w0;  off = 0; }
  else if (i < 262144)  { src = w1;  off = 196608; }
  else if (i < 327680)  { src = w2;  off = 262144; }
  else if (i < 393216)  { src = w3;  off = 327680; }
  else if (i < 786432)  { src = x;   off = 393216; }
  else if (i < 1310720) { src = xc;  off = 786432; }
  else                  { src = dxc; off = 1310720; }
  f32x4 v = *(const f32x4*)(src + (i - off) * 4);
  ushort4 o = { f2bf(v[0]), f2bf(v[1]), f2bf(v[2]), f2bf(v[3]) };
  *(ushort4*)(dst + i * 4) = o;
}

// ---------------------------------------------------------------------------
// 128x128-tile GEMM block body (m97 structure). K=512 fixed, row stride 512.
// C[m,n] = sum_k A[m,k]*W[n,k]. 4 waves in 2x2; wave = 64x64 (16 f32x4 acc).
// LDS: A-tile 128x32 + W-tile 128x32 (bf16, 8KB each), staged with
// global_load_lds width 16. Chunk XOR swizzle: 16B chunk of (row, cseg)
// stored at position row*4 + (cseg ^ ((row>>1)&3)) -> ds_read_b128 fragment
// reads are 2-way per bank group (free, m136).
// ---------------------------------------------------------------------------
__device__ __forceinline__ void gemm128_mac(const ushort* __restrict__ A,
                                            const ushort* __restrict__ W,
                                            int mt, int nt, ushort* lds,
                                            f32x4* acc) {
  int t = threadIdx.x;
  ushort* ldsA = lds;
  ushort* ldsW = lds + 4096;

  // staging: thread t handles chunks p0 = t and p1 = t + 256 of each tile
  int p0 = t, p1 = t + 256;
  int r0 = p0 >> 2, r1 = p1 >> 2;
  int c0 = (p0 & 3) ^ ((r0 >> 1) & 3);
  int c1 = (p1 & 3) ^ ((r1 >> 1) & 3);
  const ushort* ga0 = A + (size_t)(mt * 128 + r0) * 512 + c0 * 8;
  const ushort* ga1 = A + (size_t)(mt * 128 + r1) * 512 + c1 * 8;
  const ushort* gw0 = W + (size_t)(nt * 128 + r0) * 512 + c0 * 8;
  const ushort* gw1 = W + (size_t)(nt * 128 + r1) * 512 + c1 * 8;
  ushort* la0 = ldsA + p0 * 8;
  ushort* la1 = ldsA + p1 * 8;
  ushort* lw0 = ldsW + p0 * 8;
  ushort* lw1 = ldsW + p1 * 8;

  // fragment read bases
  int lane = t & 63, l15 = lane & 15, kg = lane >> 4;
  int wv = t >> 6;
  int mh = (wv >> 1) * 64, nh = (wv & 1) * 64;
  int swz = kg ^ ((l15 >> 1) & 3);
  const ushort* fa = ldsA + (mh + l15) * 32 + swz * 8;
  const ushort* fw = ldsW + (nh + l15) * 32 + swz * 8;

  for (int ks = 0; ks < 16; ++ks) {
    int ko = ks * 32;
    __builtin_amdgcn_global_load_lds(GPTR(ga0 + ko), SPTR(la0), 16, 0, 0);
    __builtin_amdgcn_global_load_lds(GPTR(ga1 + ko), SPTR(la1), 16, 0, 0);
    __builtin_amdgcn_global_load_lds(GPTR(gw0 + ko), SPTR(lw0), 16, 0, 0);
    __builtin_amdgcn_global_load_lds(GPTR(gw1 + ko), SPTR(lw1), 16, 0, 0);
    __syncthreads();
    bf16x8 af[4], wf[4];
#pragma unroll
    for (int i = 0; i < 4; ++i) af[i] = *(const bf16x8*)(fa + i * 512);
#pragma unroll
    for (int i = 0; i < 4; ++i) wf[i] = *(const bf16x8*)(fw + i * 512);
#pragma unroll
    for (int mi = 0; mi < 4; ++mi)
#pragma unroll
      for (int ni = 0; ni < 4; ++ni)
        acc[mi * 4 + ni] =
            __builtin_amdgcn_mfma_f32_16x16x32_bf16(af[mi], wf[ni], acc[mi * 4 + ni], 0, 0, 0);
    __syncthreads();
  }
}

// OUTMODE 0: C bf16 row-major [*,N]. 1: CT bf16 transposed CT[col*TM+row]
// (CT may be pre-offset). 2: Cf f32 row-major + bias.
template<int OUTMODE>
__device__ __forceinline__ void gemm128(const ushort* __restrict__ A,
                                        const ushort* __restrict__ W,
                                        ushort* __restrict__ C,
                                        ushort* __restrict__ CT,
                                        float* __restrict__ Cf,
                                        const float* __restrict__ bias,
                                        int mt, int nt, int N, long TM,
                                        ushort* lds) {
  f32x4 acc[16] = {{0,0,0,0},{0,0,0,0},{0,0,0,0},{0,0,0,0},
                   {0,0,0,0},{0,0,0,0},{0,0,0,0},{0,0,0,0},
                   {0,0,0,0},{0,0,0,0},{0,0,0,0},{0,0,0,0},
                   {0,0,0,0},{0,0,0,0},{0,0,0,0},{0,0,0,0}};
  gemm128_mac(A, W, mt, nt, lds, acc);

  int lane = threadIdx.x & 63, l15 = lane & 15, kg = lane >> 4;
  int wv = threadIdx.x >> 6;
  int Rw = mt * 128 + (wv >> 1) * 64;
  int Cw = nt * 128 + (wv & 1) * 64;
#pragma unroll
  for (int mi = 0; mi < 4; ++mi) {
    int row = Rw + mi * 16 + kg * 4;
#pragma unroll
    for (int ni = 0; ni < 4; ++ni) {
      f32x4 v = acc[mi * 4 + ni];
      int col = Cw + ni * 16 + l15;
      if (OUTMODE == 0) {
#pragma unroll
        for (int r = 0; r < 4; ++r) C[(size_t)(row + r) * N + col] = f2bf(v[r]);
      } else if (OUTMODE == 1) {
        ushort4 o = { f2bf(v[0]), f2bf(v[1]), f2bf(v[2]), f2bf(v[3]) };
        *(ushort4*)(CT + (long)col * TM + row) = o;
      } else {
        float bv = bias[col];
#pragma unroll
        for (int r = 0; r < 4; ++r) Cf[(size_t)(row + r) * N + col] = v[r] + bv;
      }
    }
  }
}

// Fused input GEMMs. blocks [0,288): qkv = x@qkv_w.T (24m x 12n tiles;
// n-tiles >=8 are self-V cols -> transposed into vselfT).
// [288,416): kctx = dx_ctx@k_w.T (32x4). [416,544): vctx^T (32x4).
__global__ __launch_bounds__(256) void gemm3(const ushort* __restrict__ xb,
                                             const ushort* __restrict__ dxb,
                                             const ushort* __restrict__ xcb,
                                             const ushort* __restrict__ qkvwb,
                                             const ushort* __restrict__ kwb,
                                             const ushort* __restrict__ vwb,
                                             ushort* __restrict__ qkv,
                                             ushort* __restrict__ vselfT,
                                             ushort* __restrict__ kctx,
                                             ushort* __restrict__ vctxT) {
  __shared__ ushort lds[8192];
  int blk = blockIdx.x;
  if (blk < 288) {
    int mt = blk % 24, nt = blk / 24;
    if (nt < 8)
      gemm128<0>(xb, qkvwb, qkv, nullptr, nullptr, nullptr, mt, nt, 1536, 0, lds);
    else
      gemm128<1>(xb, qkvwb, nullptr, vselfT - (size_t)1024 * 3072, nullptr, nullptr,
                 mt, nt, 1536, 3072, lds);
  } else if (blk < 416) {
    int r = blk - 288;
    gemm128<0>(dxb, kwb, kctx, nullptr, nullptr, nullptr, r % 32, r / 32, 512, 0, lds);
  } else {
    int r = blk - 416;
    gemm128<1>(xcb, vwb, nullptr, vctxT, nullptr, nullptr, r % 32, r / 32, 512, 4096, lds);
  }
}

__global__ __launch_bounds__(256) void gemm_proj(const ushort* __restrict__ aout,
                                                 const ushort* __restrict__ pwb,
                                                 const float* __restrict__ bias,
                                                 float* __restrict__ out) {
  __shared__ ushort lds[8192];
  int blk = blockIdx.x;  // 96 blocks: 24 mt x 4 nt
  gemm128<2>(aout, pwb, nullptr, nullptr, out, bias, blk % 24, blk / 24, 512, 0, lds);
}

// Flash attention, S^T orientation. Block = (b, h, frame t0); 4 waves x 16 q.
__global__ __launch_bounds__(256) void flash_attn(const ushort* __restrict__ qkv,
                                                  const ushort* __restrict__ kctx,
                                                  const ushort* __restrict__ vctxT,
                                                  const ushort* __restrict__ vselfT,
                                                  const int* __restrict__ ctx_mask,
                                                  ushort* __restrict__ aout) {
  __shared__ ushort Pt[4][16 * 72];  // per-wave P^T strip
  int blk = blockIdx.x;              // b*96 + h*12 + t0
  int t0 = blk % NT0;
  int h  = (blk / NT0) % HH;
  int b  = blk / (NT0 * HH);
  int tid = threadIdx.x, wv = tid >> 6, lane = tid & 63;
  int l15 = lane & 15, kg = lane >> 4;

  int qrow = b * NQ + t0 * LL + wv * 16 + l15;
  const ushort* qp = qkv + (size_t)qrow * 1536 + h * HD + kg * 8;
  bf16x8 q0 = *(const bf16x8*)qp;
  bf16x8 q1 = *(const bf16x8*)(qp + 32);

  f32x4 acc[4] = {{0,0,0,0},{0,0,0,0},{0,0,0,0},{0,0,0,0}};
  float Mr = -INFINITY, Lr = 0.f;
  ushort* myPt = &Pt[wv][0];

  for (int kt = 0; kt <= TT; ++kt) {
    const ushort* kbase; int kstr;
    if (kt < TT) {
      if (!(ctx_mask[b * TT + kt] != 0 && kt != t0 + 4)) continue;
      kbase = kctx + (size_t)(b * NCTX + kt * LL) * CC + h * HD;
      kstr = CC;
    } else {
      kbase = qkv + (size_t)(b * NQ + t0 * LL) * 1536 + CC + h * HD;
      kstr = 1536;
    }

    f32x4 s[4];
#pragma unroll
    for (int st = 0; st < 4; ++st) {
      const ushort* kp = kbase + (size_t)(st * 16 + l15) * kstr + kg * 8;
      bf16x8 k0 = *(const bf16x8*)kp;
      bf16x8 k1 = *(const bf16x8*)(kp + 32);
      f32x4 z = {0, 0, 0, 0};
      z = __builtin_amdgcn_mfma_f32_16x16x32_bf16(k0, q0, z, 0, 0, 0);
      z = __builtin_amdgcn_mfma_f32_16x16x32_bf16(k1, q1, z, 0, 0, 0);
      s[st] = z * 0.125f;
    }

    float tmax = -INFINITY;
#pragma unroll
    for (int st = 0; st < 4; ++st)
#pragma unroll
      for (int r = 0; r < 4; ++r) tmax = fmaxf(tmax, s[st][r]);
    tmax = fmaxf(tmax, __shfl_xor(tmax, 16, 64));
    tmax = fmaxf(tmax, __shfl_xor(tmax, 32, 64));
    float Mn = fmaxf(Mr, tmax);
    float alpha = __expf(Mr - Mn);
    Mr = Mn;
    float tsum = 0.f;
#pragma unroll
    for (int st = 0; st < 4; ++st)
#pragma unroll
      for (int r = 0; r < 4; ++r) {
        float p = __expf(s[st][r] - Mr);
        s[st][r] = p;
        tsum += p;
      }
    tsum += __shfl_xor(tsum, 16, 64);
    tsum += __shfl_xor(tsum, 32, 64);
    Lr = Lr * alpha + tsum;
#pragma unroll
    for (int d = 0; d < 4; ++d) acc[d] *= alpha;

#pragma unroll
    for (int st = 0; st < 4; ++st) {
      ushort4 pk = { f2bf(s[st][0]), f2bf(s[st][1]), f2bf(s[st][2]), f2bf(s[st][3]) };
      *(ushort4*)(myPt + l15 * 72 + st * 16 + kg * 4) = pk;
    }

    const ushort* vtb; int vtN;
    if (kt < TT) { vtb = vctxT + (size_t)h * HD * (BB * NCTX) + b * NCTX + kt * LL; vtN = BB * NCTX; }
    else         { vtb = vselfT + (size_t)h * HD * (BB * NQ) + b * NQ + t0 * LL;   vtN = BB * NQ; }
#pragma unroll
    for (int kc = 0; kc < 2; ++kc) {
      bf16x8 pb = *(const bf16x8*)(myPt + l15 * 72 + kc * 32 + kg * 8);
#pragma unroll
      for (int d = 0; d < 4; ++d) {
        const ushort* vp = vtb + (size_t)(d * 16 + l15) * vtN + kc * 32 + kg * 8;
        bf16x8 vf = *(const bf16x8*)vp;
        acc[d] = __builtin_amdgcn_mfma_f32_16x16x32_bf16(vf, pb, acc[d], 0, 0, 0);
      }
    }
  }

  float inv = 1.f / Lr;
  int orow = b * NQ + t0 * LL + wv * 16 + l15;
#pragma unroll
  for (int d = 0; d < 4; ++d) {
    ushort4 o = { f2bf(acc[d][0] * inv), f2bf(acc[d][1] * inv),
                  f2bf(acc[d][2] * inv), f2bf(acc[d][3] * inv) };
    *(ushort4*)(aout + (size_t)orow * CC + h * HD + d * 16 + kg * 4) = o;
  }
}

extern "C" void kernel_launch(void* const* d_in, const int* in_sizes, int n_in,
                              void* d_out, int out_size, void* d_ws, size_t ws_size,
                              hipStream_t stream) {
  const float* x        = (const float*)d_in[0];
  const float* x_ctx    = (const float*)d_in[1];
  const float* dx_ctx   = (const float*)d_in[2];
  const int*   ctx_mask = (const int*)d_in[3];
  const float* qkv_w    = (const float*)d_in[4];
  const float* k_w      = (const float*)d_in[5];
  const float* v_w      = (const float*)d_in[6];
  const float* proj_w   = (const float*)d_in[7];
  const float* proj_b   = (const float*)d_in[8];
  float* out = (float*)d_out;

  ushort* ws = (ushort*)d_ws;   // element offsets (bf16)
  ushort* qkvwb  = ws;                    //  786432
  ushort* kwb    = ws + 786432;           //  262144
  ushort* vwb    = ws + 1048576;          //  262144
  ushort* pwb    = ws + 1310720;          //  262144
  ushort* xb     = ws + 1572864;          // 1572864  (3072x512)
  ushort* xcb    = ws + 3145728;          // 2097152  (4096x512)
  ushort* dxb    = ws + 5242880;          // 2097152  (4096x512)
  ushort* qkv    = ws + 7340032;          // 3072x1536
  ushort* kctx   = ws + 12058624;         // 4096x512
  ushort* vctxT  = ws + 14155776;         // 512x4096
  ushort* vselfT = ws + 16252928;         // 512x3072
  ushort* aout   = ws + 17825792;         // 3072x512  (end 19398656 el = 38.8MB)

  cvt_all<<<7168, 256, 0, stream>>>(qkv_w, k_w, v_w, proj_w, x, x_ctx, dx_ctx, ws);
  gemm3<<<544, 256, 0, stream>>>(xb, dxb, xcb, qkvwb, kwb, vwb,
                                 qkv, vselfT, kctx, vctxT);
  flash_attn<<<BB * HH * NT0, 256, 0, stream>>>(qkv, kctx, vctxT, vselfT, ctx_mask, aout);
  gemm_proj<<<96, 256, 0, stream>>>(aout, pwb, proj_b, out);
}